// Round 1
// baseline (467.420 us; speedup 1.0000x reference)
//
#include <hip/hip_runtime.h>

typedef _Float16 f16;
typedef __attribute__((ext_vector_type(8))) _Float16 half8;
typedef __attribute__((ext_vector_type(2))) _Float16 half2v;
typedef __attribute__((ext_vector_type(4))) float float4v;

#define MODE_QK 0
#define MODE_V 1
#define MODE_PV 2
#define MODE_PROJ 3

// B=8 N=512 P=16 C=512 H=8 HD=64 E=1024
// ws layout (bytes):
//   0         : xf16 [B,N,P,C] f16 (67108864)   -> reused as ypre [B,N,P,C]
//   67108864  : vT   [B,H,E',N] f16 (67108864)  (E' channel order = p*64+dd)
//   134217728 : xmean[B,N,C]   f16 (4194304)
//   138412032 : WT   [1536,512]f16 (1572864)    (Wqkv transposed)
//   139984896 : WpT  [512,512] f16 (524288)
//   140509184 : q    [B,H,N,64]f16 (4194304)
//   144703488 : k    [B,H,N,64]f16 (4194304)
//   148897792 : P    [B,H,N,N] f16 (33554432)

__device__ __forceinline__ void gload16(const f16* g, f16* l) {
    __builtin_amdgcn_global_load_lds(
        (const __attribute__((address_space(1))) void*)g,
        (__attribute__((address_space(3))) void*)l, 16, 0, 0);
}

// merged: blocks [0,4096) do x prep; blocks [4096,8192) do weight transpose
__global__ __launch_bounds__(256) void prep_kernel(
    const float* __restrict__ x, const float* __restrict__ mask,
    const float* __restrict__ Wqkv, const float* __restrict__ Wproj,
    f16* __restrict__ xf, f16* __restrict__ xmean,
    f16* __restrict__ WT, f16* __restrict__ WpT)
{
    if (blockIdx.x >= 4096) {
        int idx = (blockIdx.x - 4096) * 256 + threadIdx.x;   // 1048576 total
        if (idx < 1536 * 512) {
            int d = idx >> 9, c = idx & 511;
            WT[idx] = (f16)Wqkv[c * 1536 + d];
        } else {
            int i2 = idx - 1536 * 512;
            int d = i2 >> 9, c = i2 & 511;
            WpT[i2] = (f16)Wproj[c * 512 + d];
        }
        return;
    }
    int bn = blockIdx.x;           // b*512+n
    int t = threadIdx.x;           // 256
    const float* xrow = x + (size_t)bn * 16 * 512;
    const float* mrow = mask + (size_t)bn * 16;
    float msum = 0.f;
    #pragma unroll
    for (int p = 0; p < 16; p++) msum += mrow[p];
    int c = t * 2;
    float a0 = 0.f, a1 = 0.f;
    #pragma unroll
    for (int p = 0; p < 16; p++) {
        float2 v = *(const float2*)(xrow + p * 512 + c);
        float m = mrow[p];
        a0 += m * v.x; a1 += m * v.y;
        half2v h; h[0] = (f16)v.x; h[1] = (f16)v.y;
        *(half2v*)(xf + (size_t)bn * 16 * 512 + p * 512 + c) = h;
    }
    float inv = 1.f / msum;
    half2v hm; hm[0] = (f16)(a0 * inv); hm[1] = (f16)(a1 * inv);
    *(half2v*)(xmean + (size_t)bn * 512 + c) = hm;
}

// 128x128 tile, K=512, BK=32, 256 threads = 4 waves in 2x2; each wave 64x64
// (4x4 fragments of 16x16x32). A,B staged via global_load_lds width=16.
// MFMA A/B frag: row = lane&15, k = (lane>>4)*8 + j.
// C/D: col = lane&15, row = (lane>>4)*4 + reg.
// Epilogue: LDS-bounce (row pad +8 f16 / +4 f32 keeps ds ops ~2-way) ->
// coalesced 16B stores instead of 64 scalar 2B/4B stores per thread.
template<int MODE>
__global__ __launch_bounds__(256) void gemm128(
    const f16* __restrict__ pA, const f16* __restrict__ pA2,
    const f16* __restrict__ pB,
    f16* __restrict__ outa, f16* __restrict__ outb,
    float* __restrict__ outf, const float* __restrict__ bias)
{
    __shared__ __align__(16) f16 sm[8192];   // 16 KB: As(8K) + Bs(8K); reused by bounce
    f16* As = sm;
    f16* Bs = sm + 4096;
    const int t = threadIdx.x;
    const int lane = t & 63;
    const int w = t >> 6;
    const int wm = w & 1, wn = w >> 1;
    const int quad = lane >> 4, l15 = lane & 15;

    const int n0 = blockIdx.x * 128;   // col tile fastest -> A reuse in L2
    const int m0 = blockIdx.y * 128;
    int vb = 0, vp = 0, z = 0;

    const f16* Abase; size_t sA;
    const f16* Bbase; size_t sB;
    if constexpr (MODE == MODE_QK) {
        if (n0 < 512) { Abase = pA;  sA = 8192; }   // x p=0 slice
        else          { Abase = pA2; sA = 512;  }   // xmean
        Bbase = pB; sB = 512;                       // WT rows
    } else if constexpr (MODE == MODE_V) {
        z = blockIdx.z; vb = z >> 4; vp = z & 15;
        Abase = pA; sA = 512;                       // WvT rows
        Bbase = pB + ((size_t)vb * 512 * 16 + vp) * 512; sB = 8192; // x[b,:,p,:]
    } else if constexpr (MODE == MODE_PV) {
        z = blockIdx.z;                             // bh
        Abase = pA + (size_t)z * 512 * 512; sA = 512;   // P rows
        Bbase = pB + (size_t)z * 1024 * 512; sB = 512;  // vT rows
    } else {
        Abase = pA; sA = 512;                       // ypre rows
        Bbase = pB; sB = 512;                       // WpT rows
    }

    // staging: A tile = 8 chunks of 16 rows (1024 B each); wave w owns
    // chunks {w, w+4}. lane covers row-in-chunk = lane>>2, k = (lane&3)*8.
    const int rlo = (lane >> 2), kof = (lane & 3) * 8;
    const f16* ga0 = Abase + (size_t)(m0 + w * 16 + rlo) * sA + kof;
    const f16* ga1 = Abase + (size_t)(m0 + (w + 4) * 16 + rlo) * sA + kof;
    const f16* gb0 = Bbase + (size_t)(n0 + w * 16 + rlo) * sB + kof;
    const f16* gb1 = Bbase + (size_t)(n0 + (w + 4) * 16 + rlo) * sB + kof;
    f16* lA0 = As + w * 512;        // wave-uniform LDS bases
    f16* lA1 = As + (w + 4) * 512;
    f16* lB0 = Bs + w * 512;
    f16* lB1 = Bs + (w + 4) * 512;

    float4v acc[4][4];
    #pragma unroll
    for (int i = 0; i < 4; i++)
        #pragma unroll
        for (int j = 0; j < 4; j++)
            acc[i][j] = (float4v){0.f, 0.f, 0.f, 0.f};

    for (int kt = 0; kt < 16; kt++) {
        __syncthreads();           // prior reads done before overwrite
        gload16(ga0, lA0); gload16(ga1, lA1);
        gload16(gb0, lB0); gload16(gb1, lB1);
        ga0 += 32; ga1 += 32; gb0 += 32; gb1 += 32;
        __syncthreads();           // compiler drains vmcnt before barrier
        half8 af[4], bf[4];
        #pragma unroll
        for (int mi = 0; mi < 4; mi++)
            af[mi] = *(const half8*)&As[(wm * 64 + mi * 16 + l15) * 32 + quad * 8];
        #pragma unroll
        for (int ni = 0; ni < 4; ni++)
            bf[ni] = *(const half8*)&Bs[(wn * 64 + ni * 16 + l15) * 32 + quad * 8];
        #pragma unroll
        for (int mi = 0; mi < 4; mi++)
            #pragma unroll
            for (int ni = 0; ni < 4; ni++)
                acc[mi][ni] = __builtin_amdgcn_mfma_f32_16x16x32_f16(
                    af[mi], bf[ni], acc[mi][ni], 0, 0, 0);
    }

    __syncthreads();   // all waves done reading As/Bs; reuse sm for bounce

    if constexpr (MODE == MODE_PROJ) {
        // 8 chunks of 16 rows x 128 f32 (row stride 132 -> ~2-way banks)
        float* pf = (float*)sm;                    // 2112 f32 = 8448 B used
        const int rp = t >> 4, cp = (t & 15) * 8;  // readback mapping
        float4v bb0 = *(const float4v*)&bias[n0 + cp];
        float4v bb1 = *(const float4v*)&bias[n0 + cp + 4];
        #pragma unroll
        for (int ci = 0; ci < 8; ci++) {
            if (wm == (ci >> 2)) {
                int mi = ci & 3;
                #pragma unroll
                for (int ni = 0; ni < 4; ni++)
                    #pragma unroll
                    for (int i = 0; i < 4; i++)
                        pf[(quad * 4 + i) * 132 + wn * 64 + ni * 16 + l15] =
                            acc[mi][ni][i];
            }
            __syncthreads();
            float4v v0 = *(const float4v*)&pf[rp * 132 + cp];
            float4v v1 = *(const float4v*)&pf[rp * 132 + cp + 4];
            size_t gb = (size_t)(m0 + ci * 16 + rp) * 512 + n0 + cp;
            *(float4v*)&outf[gb] = v0 + bb0;
            *(float4v*)&outf[gb + 4] = v1 + bb1;
            __syncthreads();
        }
    } else {
        // 4 chunks of 32 rows x 128 f16 (row stride 136 -> ~2-way banks)
        f16* ph = sm;                              // 4352 f16 = 8704 B used
        const int rp = t >> 3, cp = (t & 7) * 16;  // readback mapping
        #pragma unroll
        for (int ci = 0; ci < 4; ci++) {
            if (wm == (ci >> 1)) {
                #pragma unroll
                for (int mh = 0; mh < 2; mh++) {
                    int mi = (ci & 1) * 2 + mh;
                    #pragma unroll
                    for (int ni = 0; ni < 4; ni++)
                        #pragma unroll
                        for (int i = 0; i < 4; i++)
                            ph[(mh * 16 + quad * 4 + i) * 136 + wn * 64 + ni * 16 + l15] =
                                (f16)acc[mi][ni][i];
                }
            }
            __syncthreads();
            int gr = m0 + ci * 32 + rp;            // tile row
            #pragma unroll
            for (int s = 0; s < 2; s++) {
                half8 v = *(const half8*)&ph[rp * 136 + cp + s * 8];
                int gc = n0 + cp + s * 8;          // tile col
                if constexpr (MODE == MODE_QK) {
                    int b = gr >> 9, n = gr & 511;
                    if (gc < 512)
                        *(half8*)&outa[(((size_t)(b * 8 + (gc >> 6))) * 512 + n) * 64 + (gc & 63)] = v;
                    else {
                        int jj = gc - 512;
                        *(half8*)&outb[(((size_t)(b * 8 + (jj >> 6))) * 512 + n) * 64 + (jj & 63)] = v;
                    }
                } else if constexpr (MODE == MODE_V) {
                    int h = gr >> 6, dd = gr & 63;   // e' order: p*64+dd
                    *(half8*)&outa[(((size_t)(vb * 8 + h)) * 1024 + vp * 64 + dd) * 512 + gc] = v;
                } else { // MODE_PV: direct ypre store, e' = p*64+dd
                    int p = gc >> 6, dd = gc & 63;
                    int b = z >> 3, h = z & 7;
                    *(half8*)&outa[((size_t)(b * 512 + gr) * 16 + p) * 512 + h * 64 + dd] = v;
                }
            }
            __syncthreads();
        }
    }
}

// Fused S = q k^T * 0.125 and row softmax, writes P (f16, normalized).
// grid (8 ntiles, 64 bh); block 256; wave w owns q-rows n0+16w..+16, all 512 cols.
// k staged in 4 chunks of [128][64] f16 (16 KB) via global_load_lds with
// both-sides XOR swizzle (col16 ^= row&7) so ds_read_b128 is ~2-way, not 16-way.
// q fragments loaded directly from global (L2-hot, 2 loads).
// P written via per-wave LDS bounce ([16][264] f16) as half8 stores.
__global__ __launch_bounds__(256) void qk_softmax_kernel(
    const f16* __restrict__ q, const f16* __restrict__ k, f16* __restrict__ Pout)
{
    __shared__ __align__(16) f16 sm[16896];   // 33 KB: k-chunk 8192 f16 + bounce 4*4224
    const int t = threadIdx.x;
    const int lane = t & 63, w = t >> 6;
    const int quad = lane >> 4, l15 = lane & 15;
    const int bh = blockIdx.y;
    const int n0 = blockIdx.x * 64;

    const f16* kbase = k + (size_t)bh * 512 * 64;
    const f16* qp = q + ((size_t)bh * 512 + n0 + w * 16 + l15) * 64 + quad * 8;
    half8 a0 = *(const half8*)qp;
    half8 a1 = *(const half8*)(qp + 32);

    float4v acc[32];
    #pragma unroll
    for (int f = 0; f < 32; f++) acc[f] = (float4v){0.f, 0.f, 0.f, 0.f};

    const int srow = lane >> 3, scol = lane & 7;
    #pragma unroll
    for (int c = 0; c < 4; c++) {
        __syncthreads();           // prior chunk reads done
        #pragma unroll
        for (int i = 0; i < 4; i++) {
            int ci2 = w * 4 + i;
            int row = ci2 * 8 + srow;
            // linear LDS dest; source pre-swizzled (rule: both-sides-or-neither)
            gload16(kbase + c * 8192 + row * 64 + ((scol ^ (row & 7)) << 3),
                    sm + ci2 * 512 + lane * 8);
        }
        __syncthreads();
        #pragma unroll
        for (int fl = 0; fl < 8; fl++) {
            int row16 = fl * 16 + l15;
            int sw = row16 & 7;
            half8 b0 = *(const half8*)&sm[row16 * 64 + ((quad ^ sw) << 3)];
            half8 b1 = *(const half8*)&sm[row16 * 64 + (((quad + 4) ^ sw) << 3)];
            acc[c * 8 + fl] = __builtin_amdgcn_mfma_f32_16x16x32_f16(
                a0, b0, acc[c * 8 + fl], 0, 0, 0);
            acc[c * 8 + fl] = __builtin_amdgcn_mfma_f32_16x16x32_f16(
                a1, b1, acc[c * 8 + fl], 0, 0, 0);
        }
    }

    float mx0 = -3e38f, mx1 = -3e38f, mx2 = -3e38f, mx3 = -3e38f;
    #pragma unroll
    for (int f = 0; f < 32; f++) {
        mx0 = fmaxf(mx0, acc[f][0]); mx1 = fmaxf(mx1, acc[f][1]);
        mx2 = fmaxf(mx2, acc[f][2]); mx3 = fmaxf(mx3, acc[f][3]);
    }
    #pragma unroll
    for (int off = 1; off < 16; off <<= 1) {
        mx0 = fmaxf(mx0, __shfl_xor(mx0, off));
        mx1 = fmaxf(mx1, __shfl_xor(mx1, off));
        mx2 = fmaxf(mx2, __shfl_xor(mx2, off));
        mx3 = fmaxf(mx3, __shfl_xor(mx3, off));
    }
    float s0 = 0.f, s1 = 0.f, s2 = 0.f, s3 = 0.f;
    #pragma unroll
    for (int f = 0; f < 32; f++) {
        float e0 = __expf(0.125f * (acc[f][0] - mx0));
        float e1 = __expf(0.125f * (acc[f][1] - mx1));
        float e2 = __expf(0.125f * (acc[f][2] - mx2));
        float e3 = __expf(0.125f * (acc[f][3] - mx3));
        acc[f][0] = e0; acc[f][1] = e1; acc[f][2] = e2; acc[f][3] = e3;
        s0 += e0; s1 += e1; s2 += e2; s3 += e3;
    }
    #pragma unroll
    for (int off = 1; off < 16; off <<= 1) {
        s0 += __shfl_xor(s0, off);
        s1 += __shfl_xor(s1, off);
        s2 += __shfl_xor(s2, off);
        s3 += __shfl_xor(s3, off);
    }
    float r0 = 1.f / s0, r1 = 1.f / s1, r2 = 1.f / s2, r3 = 1.f / s3;

    __syncthreads();               // all waves done with k chunks; reuse sm
    f16* pb = sm + w * 4224;       // per-wave [16][264] f16 bounce
    const int rr = lane >> 2, cb = (lane & 3) * 64;
    #pragma unroll
    for (int cc = 0; cc < 2; cc++) {
        #pragma unroll
        for (int ff = 0; ff < 16; ff++) {
            int f = cc * 16 + ff;
            pb[(quad * 4 + 0) * 264 + ff * 16 + l15] = (f16)(acc[f][0] * r0);
            pb[(quad * 4 + 1) * 264 + ff * 16 + l15] = (f16)(acc[f][1] * r1);
            pb[(quad * 4 + 2) * 264 + ff * 16 + l15] = (f16)(acc[f][2] * r2);
            pb[(quad * 4 + 3) * 264 + ff * 16 + l15] = (f16)(acc[f][3] * r3);
        }
        size_t gb = ((size_t)bh * 512 + n0 + w * 16 + rr) * 512 + cc * 256 + cb;
        #pragma unroll
        for (int s = 0; s < 8; s++) {
            half8 v = *(const half8*)&pb[rr * 264 + cb + s * 8];
            *(half8*)&Pout[gb + s * 8] = v;
        }
    }
}

extern "C" void kernel_launch(void* const* d_in, const int* in_sizes, int n_in,
                              void* d_out, int out_size, void* d_ws, size_t ws_size,
                              hipStream_t stream)
{
    (void)in_sizes; (void)n_in; (void)out_size; (void)ws_size;
    const float* x     = (const float*)d_in[0];
    const float* mask  = (const float*)d_in[1];
    // d_in[2] lens, d_in[3] lens_mask: unused by the reference forward
    const float* Wqkv  = (const float*)d_in[4];
    const float* Wproj = (const float*)d_in[5];
    const float* bproj = (const float*)d_in[6];
    float* out = (float*)d_out;
    char* ws = (char*)d_ws;

    f16* xf16  = (f16*)(ws + 0);
    f16* vT    = (f16*)(ws + 67108864);
    f16* xmean = (f16*)(ws + 134217728);
    f16* WT    = (f16*)(ws + 138412032);
    f16* WpT   = (f16*)(ws + 139984896);
    f16* qb    = (f16*)(ws + 140509184);
    f16* kb    = (f16*)(ws + 144703488);
    f16* Pm    = (f16*)(ws + 148897792);
    f16* ypre  = xf16;   // xf16 dead after V GEMM; PV writes here, PROJ reads

    prep_kernel<<<dim3(8192), dim3(256), 0, stream>>>(
        x, mask, Wqkv, Wproj, xf16, xmean, WT, WpT);
    gemm128<MODE_QK><<<dim3(8, 32), dim3(256), 0, stream>>>(
        xf16, xmean, WT, qb, kb, nullptr, nullptr);
    gemm128<MODE_V><<<dim3(4, 4, 128), dim3(256), 0, stream>>>(
        WT + 1024 * 512, nullptr, xf16, vT, nullptr, nullptr, nullptr);
    qk_softmax_kernel<<<dim3(8, 64), dim3(256), 0, stream>>>(qb, kb, Pm);
    gemm128<MODE_PV><<<dim3(8, 4, 64), dim3(256), 0, stream>>>(
        Pm, nullptr, vT, ypre, nullptr, nullptr, nullptr);
    gemm128<MODE_PROJ><<<dim3(4, 512), dim3(256), 0, stream>>>(
        ypre, nullptr, WpT, nullptr, nullptr, out, bproj);
}

// Round 2
// 438.608 us; speedup vs baseline: 1.0657x; 1.0657x over previous
//
#include <hip/hip_runtime.h>

typedef _Float16 f16;
typedef __attribute__((ext_vector_type(8))) _Float16 half8;
typedef __attribute__((ext_vector_type(2))) _Float16 half2v;
typedef __attribute__((ext_vector_type(4))) float float4v;

#define MODE_QK 0
#define MODE_V 1
#define MODE_PV 2
#define MODE_PROJ 3

// B=8 N=512 P=16 C=512 H=8 HD=64 E=1024
// ws layout (bytes):
//   0         : xf16 [B,N,P,C] f16 (67108864)   -> reused as ypre [B,N,P,C]
//   67108864  : vT   [B,H,E',N] f16 (67108864)  (E' channel order = p*64+dd)
//   134217728 : xmean[B,N,C]   f16 (4194304)
//   138412032 : WT   [1536,512]f16 (1572864)    (Wqkv transposed)
//   139984896 : WpT  [512,512] f16 (524288)
//   140509184 : q    [B,H,N,64]f16 (4194304)
//   144703488 : k    [B,H,N,64]f16 (4194304)
//   148897792 : P    [B,H,N,N] f16 (33554432)

__device__ __forceinline__ void gload16(const f16* g, f16* l) {
    __builtin_amdgcn_global_load_lds(
        (const __attribute__((address_space(1))) void*)g,
        (__attribute__((address_space(3))) void*)l, 16, 0, 0);
}

// merged: blocks [0,4096) do x prep; blocks [4096,8192) do weight transpose
__global__ __launch_bounds__(256) void prep_kernel(
    const float* __restrict__ x, const float* __restrict__ mask,
    const float* __restrict__ Wqkv, const float* __restrict__ Wproj,
    f16* __restrict__ xf, f16* __restrict__ xmean,
    f16* __restrict__ WT, f16* __restrict__ WpT)
{
    if (blockIdx.x >= 4096) {
        int idx = (blockIdx.x - 4096) * 256 + threadIdx.x;   // 1048576 total
        if (idx < 1536 * 512) {
            int d = idx >> 9, c = idx & 511;
            WT[idx] = (f16)Wqkv[c * 1536 + d];
        } else {
            int i2 = idx - 1536 * 512;
            int d = i2 >> 9, c = i2 & 511;
            WpT[i2] = (f16)Wproj[c * 512 + d];
        }
        return;
    }
    int bn = blockIdx.x;           // b*512+n
    int t = threadIdx.x;           // 256
    const float* xrow = x + (size_t)bn * 16 * 512;
    const float* mrow = mask + (size_t)bn * 16;
    float msum = 0.f;
    #pragma unroll
    for (int p = 0; p < 16; p++) msum += mrow[p];
    int c = t * 2;
    float a0 = 0.f, a1 = 0.f;
    #pragma unroll
    for (int p = 0; p < 16; p++) {
        float2 v = *(const float2*)(xrow + p * 512 + c);
        float m = mrow[p];
        a0 += m * v.x; a1 += m * v.y;
        half2v h; h[0] = (f16)v.x; h[1] = (f16)v.y;
        *(half2v*)(xf + (size_t)bn * 16 * 512 + p * 512 + c) = h;
    }
    float inv = 1.f / msum;
    half2v hm; hm[0] = (f16)(a0 * inv); hm[1] = (f16)(a1 * inv);
    *(half2v*)(xmean + (size_t)bn * 512 + c) = hm;
}

// 128x128 tile, K=512, BK=32, 256 threads = 4 waves in 2x2; each wave 64x64
// (4x4 fragments of 16x16x32). A,B staged via global_load_lds width=16 into a
// DOUBLE-BUFFERED LDS pair: per iter {barrier; issue next-tile loads; ds_read
// + MFMA current} so load latency hides under compute (2-phase, T3-minimum).
// MFMA A/B frag: row = lane&15, k = (lane>>4)*8 + j.
// C/D: col = lane&15, row = (lane>>4)*4 + reg.
// Epilogue: per-WAVE private LDS bounce (no barriers, no store-ack
// serialization) -> coalesced half8/float4 stores.
template<int MODE>
__global__ __launch_bounds__(256) void gemm128(
    const f16* __restrict__ pA, const f16* __restrict__ pA2,
    const f16* __restrict__ pB,
    f16* __restrict__ outa, f16* __restrict__ outb,
    float* __restrict__ outf, const float* __restrict__ bias)
{
    // 36864 B: K-loop uses [0,32768) as 2x(As 8KB + Bs 8KB);
    // epilogue reuses whole array as 4 per-wave bounce regions.
    __shared__ __align__(16) f16 sm[18432];
    const int t = threadIdx.x;
    const int lane = t & 63;
    const int w = t >> 6;
    const int wm = w & 1, wn = w >> 1;
    const int quad = lane >> 4, l15 = lane & 15;

    const int n0 = blockIdx.x * 128;   // col tile fastest -> A reuse in L2
    const int m0 = blockIdx.y * 128;
    int vb = 0, vp = 0, z = 0;

    const f16* Abase; size_t sA;
    const f16* Bbase; size_t sB;
    if constexpr (MODE == MODE_QK) {
        if (n0 < 512) { Abase = pA;  sA = 8192; }   // x p=0 slice
        else          { Abase = pA2; sA = 512;  }   // xmean
        Bbase = pB; sB = 512;                       // WT rows
    } else if constexpr (MODE == MODE_V) {
        z = blockIdx.z; vb = z >> 4; vp = z & 15;
        Abase = pA; sA = 512;                       // WvT rows
        Bbase = pB + ((size_t)vb * 512 * 16 + vp) * 512; sB = 8192; // x[b,:,p,:]
    } else if constexpr (MODE == MODE_PV) {
        z = blockIdx.z;                             // bh
        Abase = pA + (size_t)z * 512 * 512; sA = 512;   // P rows
        Bbase = pB + (size_t)z * 1024 * 512; sB = 512;  // vT rows
    } else {
        Abase = pA; sA = 512;                       // ypre rows
        Bbase = pB; sB = 512;                       // WpT rows
    }

    // staging: A tile = 8 chunks of 16 rows (1024 B each); wave w owns
    // chunks {w, w+4}. lane covers row-in-chunk = lane>>2, k = (lane&3)*8.
    const int rlo = (lane >> 2), kof = (lane & 3) * 8;
    const f16* ga0 = Abase + (size_t)(m0 + w * 16 + rlo) * sA + kof;
    const f16* ga1 = Abase + (size_t)(m0 + (w + 4) * 16 + rlo) * sA + kof;
    const f16* gb0 = Bbase + (size_t)(n0 + w * 16 + rlo) * sB + kof;
    const f16* gb1 = Bbase + (size_t)(n0 + (w + 4) * 16 + rlo) * sB + kof;

    float4v acc[4][4];
    #pragma unroll
    for (int i = 0; i < 4; i++)
        #pragma unroll
        for (int j = 0; j < 4; j++)
            acc[i][j] = (float4v){0.f, 0.f, 0.f, 0.f};

    // prologue: stage K-tile 0 into buffer 0
    {
        f16* d = sm;
        gload16(ga0, d + w * 512); gload16(ga1, d + (w + 4) * 512);
        gload16(gb0, d + 4096 + w * 512); gload16(gb1, d + 4096 + (w + 4) * 512);
        ga0 += 32; ga1 += 32; gb0 += 32; gb1 += 32;
    }
    int cur = 0;
    for (int kt = 0; kt < 16; kt++) {
        __syncthreads();   // drains vmcnt: buf[cur] ready (all waves); prior
                           // reads of buf[cur^1] finished -> safe to overwrite
        if (kt < 15) {
            f16* d = sm + (cur ^ 1) * 8192;
            gload16(ga0, d + w * 512); gload16(ga1, d + (w + 4) * 512);
            gload16(gb0, d + 4096 + w * 512); gload16(gb1, d + 4096 + (w + 4) * 512);
            ga0 += 32; ga1 += 32; gb0 += 32; gb1 += 32;
        }
        const f16* Asr = sm + cur * 8192;
        const f16* Bsr = Asr + 4096;
        half8 af[4], bf[4];
        #pragma unroll
        for (int mi = 0; mi < 4; mi++)
            af[mi] = *(const half8*)&Asr[(wm * 64 + mi * 16 + l15) * 32 + quad * 8];
        #pragma unroll
        for (int ni = 0; ni < 4; ni++)
            bf[ni] = *(const half8*)&Bsr[(wn * 64 + ni * 16 + l15) * 32 + quad * 8];
        #pragma unroll
        for (int mi = 0; mi < 4; mi++)
            #pragma unroll
            for (int ni = 0; ni < 4; ni++)
                acc[mi][ni] = __builtin_amdgcn_mfma_f32_16x16x32_f16(
                    af[mi], bf[ni], acc[mi][ni], 0, 0, 0);
        cur ^= 1;
    }

    __syncthreads();   // all waves done reading LDS; reuse as per-wave bounce

    if constexpr (MODE == MODE_PROJ) {
        // per-wave region: 32 rows x 68 f32 (8704 B), two 32-row chunks
        float* pwf = (float*)sm + w * 2176;
        const int rr4 = lane >> 4, c4 = (lane & 15) * 4;
        float4v bb = *(const float4v*)&bias[n0 + wn * 64 + c4];
        #pragma unroll
        for (int c2 = 0; c2 < 2; c2++) {
            #pragma unroll
            for (int mh = 0; mh < 2; mh++) {
                int mi = c2 * 2 + mh;
                #pragma unroll
                for (int ni = 0; ni < 4; ni++)
                    #pragma unroll
                    for (int i = 0; i < 4; i++)
                        pwf[(mh * 16 + quad * 4 + i) * 68 + ni * 16 + l15] =
                            acc[mi][ni][i];
            }
            // wave-local write->read; compiler inserts lgkm waits
            #pragma unroll
            for (int s = 0; s < 8; s++) {
                int r = s * 4 + rr4;
                float4v v = *(const float4v*)&pwf[r * 68 + c4];
                *(float4v*)&outf[(size_t)(m0 + wm * 64 + c2 * 32 + r) * 512 +
                                 n0 + wn * 64 + c4] = v + bb;
            }
        }
    } else {
        // per-wave region: 64 rows x 72 f16 (9216 B)
        f16* pw = sm + w * 4608;
        #pragma unroll
        for (int mi = 0; mi < 4; mi++)
            #pragma unroll
            for (int ni = 0; ni < 4; ni++)
                #pragma unroll
                for (int i = 0; i < 4; i++)
                    pw[(mi * 16 + quad * 4 + i) * 72 + ni * 16 + l15] =
                        (f16)acc[mi][ni][i];
        const int rr8 = lane >> 3, c8 = (lane & 7) * 8;
        #pragma unroll
        for (int s = 0; s < 8; s++) {
            int r = s * 8 + rr8;
            half8 v = *(const half8*)&pw[r * 72 + c8];
            int gr = m0 + wm * 64 + r;
            int gc = n0 + wn * 64 + c8;
            if constexpr (MODE == MODE_QK) {
                int b = gr >> 9, n = gr & 511;
                if (gc < 512)
                    *(half8*)&outa[(((size_t)(b * 8 + (gc >> 6))) * 512 + n) * 64 + (gc & 63)] = v;
                else {
                    int jj = gc - 512;
                    *(half8*)&outb[(((size_t)(b * 8 + (jj >> 6))) * 512 + n) * 64 + (jj & 63)] = v;
                }
            } else if constexpr (MODE == MODE_V) {
                int h = gr >> 6, dd = gr & 63;   // e' order: p*64+dd
                *(half8*)&outa[(((size_t)(vb * 8 + h)) * 1024 + vp * 64 + dd) * 512 + gc] = v;
            } else { // MODE_PV: direct ypre store, e' = p*64+dd
                int p = gc >> 6, dd = gc & 63;
                int b = z >> 3, h = z & 7;
                *(half8*)&outa[((size_t)(b * 512 + gr) * 16 + p) * 512 + h * 64 + dd] = v;
            }
        }
    }
}

// Fused S = q k^T * 0.125 and row softmax, writes P (f16, normalized).
// grid (8 ntiles, 64 bh); block 256; wave w owns q-rows n0+16w..+16, all 512 cols.
// k staged in 4 chunks of [128][64] f16 (16 KB) via global_load_lds with
// both-sides XOR swizzle (col16 ^= row&7) so ds_read_b128 is ~2-way, not 16-way.
// q fragments loaded directly from global (L2-hot, 2 loads).
// P written via per-wave LDS bounce ([16][264] f16) as half8 stores.
__global__ __launch_bounds__(256) void qk_softmax_kernel(
    const f16* __restrict__ q, const f16* __restrict__ k, f16* __restrict__ Pout)
{
    __shared__ __align__(16) f16 sm[16896];   // 33 KB: k-chunk 8192 f16 + bounce 4*4224
    const int t = threadIdx.x;
    const int lane = t & 63, w = t >> 6;
    const int quad = lane >> 4, l15 = lane & 15;
    const int bh = blockIdx.y;
    const int n0 = blockIdx.x * 64;

    const f16* kbase = k + (size_t)bh * 512 * 64;
    const f16* qp = q + ((size_t)bh * 512 + n0 + w * 16 + l15) * 64 + quad * 8;
    half8 a0 = *(const half8*)qp;
    half8 a1 = *(const half8*)(qp + 32);

    float4v acc[32];
    #pragma unroll
    for (int f = 0; f < 32; f++) acc[f] = (float4v){0.f, 0.f, 0.f, 0.f};

    const int srow = lane >> 3, scol = lane & 7;
    #pragma unroll
    for (int c = 0; c < 4; c++) {
        __syncthreads();           // prior chunk reads done
        #pragma unroll
        for (int i = 0; i < 4; i++) {
            int ci2 = w * 4 + i;
            int row = ci2 * 8 + srow;
            // linear LDS dest; source pre-swizzled (rule: both-sides-or-neither)
            gload16(kbase + c * 8192 + row * 64 + ((scol ^ (row & 7)) << 3),
                    sm + ci2 * 512 + lane * 8);
        }
        __syncthreads();
        #pragma unroll
        for (int fl = 0; fl < 8; fl++) {
            int row16 = fl * 16 + l15;
            int sw = row16 & 7;
            half8 b0 = *(const half8*)&sm[row16 * 64 + ((quad ^ sw) << 3)];
            half8 b1 = *(const half8*)&sm[row16 * 64 + (((quad + 4) ^ sw) << 3)];
            acc[c * 8 + fl] = __builtin_amdgcn_mfma_f32_16x16x32_f16(
                a0, b0, acc[c * 8 + fl], 0, 0, 0);
            acc[c * 8 + fl] = __builtin_amdgcn_mfma_f32_16x16x32_f16(
                a1, b1, acc[c * 8 + fl], 0, 0, 0);
        }
    }

    float mx0 = -3e38f, mx1 = -3e38f, mx2 = -3e38f, mx3 = -3e38f;
    #pragma unroll
    for (int f = 0; f < 32; f++) {
        mx0 = fmaxf(mx0, acc[f][0]); mx1 = fmaxf(mx1, acc[f][1]);
        mx2 = fmaxf(mx2, acc[f][2]); mx3 = fmaxf(mx3, acc[f][3]);
    }
    #pragma unroll
    for (int off = 1; off < 16; off <<= 1) {
        mx0 = fmaxf(mx0, __shfl_xor(mx0, off));
        mx1 = fmaxf(mx1, __shfl_xor(mx1, off));
        mx2 = fmaxf(mx2, __shfl_xor(mx2, off));
        mx3 = fmaxf(mx3, __shfl_xor(mx3, off));
    }
    float s0 = 0.f, s1 = 0.f, s2 = 0.f, s3 = 0.f;
    #pragma unroll
    for (int f = 0; f < 32; f++) {
        float e0 = __expf(0.125f * (acc[f][0] - mx0));
        float e1 = __expf(0.125f * (acc[f][1] - mx1));
        float e2 = __expf(0.125f * (acc[f][2] - mx2));
        float e3 = __expf(0.125f * (acc[f][3] - mx3));
        acc[f][0] = e0; acc[f][1] = e1; acc[f][2] = e2; acc[f][3] = e3;
        s0 += e0; s1 += e1; s2 += e2; s3 += e3;
    }
    #pragma unroll
    for (int off = 1; off < 16; off <<= 1) {
        s0 += __shfl_xor(s0, off);
        s1 += __shfl_xor(s1, off);
        s2 += __shfl_xor(s2, off);
        s3 += __shfl_xor(s3, off);
    }
    float r0 = 1.f / s0, r1 = 1.f / s1, r2 = 1.f / s2, r3 = 1.f / s3;

    __syncthreads();               // all waves done with k chunks; reuse sm
    f16* pb = sm + w * 4224;       // per-wave [16][264] f16 bounce
    const int rr = lane >> 2, cb = (lane & 3) * 64;
    #pragma unroll
    for (int cc = 0; cc < 2; cc++) {
        #pragma unroll
        for (int ff = 0; ff < 16; ff++) {
            int f = cc * 16 + ff;
            pb[(quad * 4 + 0) * 264 + ff * 16 + l15] = (f16)(acc[f][0] * r0);
            pb[(quad * 4 + 1) * 264 + ff * 16 + l15] = (f16)(acc[f][1] * r1);
            pb[(quad * 4 + 2) * 264 + ff * 16 + l15] = (f16)(acc[f][2] * r2);
            pb[(quad * 4 + 3) * 264 + ff * 16 + l15] = (f16)(acc[f][3] * r3);
        }
        size_t gb = ((size_t)bh * 512 + n0 + w * 16 + rr) * 512 + cc * 256 + cb;
        #pragma unroll
        for (int s = 0; s < 8; s++) {
            half8 v = *(const half8*)&pb[rr * 264 + cb + s * 8];
            *(half8*)&Pout[gb + s * 8] = v;
        }
    }
}

extern "C" void kernel_launch(void* const* d_in, const int* in_sizes, int n_in,
                              void* d_out, int out_size, void* d_ws, size_t ws_size,
                              hipStream_t stream)
{
    (void)in_sizes; (void)n_in; (void)out_size; (void)ws_size;
    const float* x     = (const float*)d_in[0];
    const float* mask  = (const float*)d_in[1];
    // d_in[2] lens, d_in[3] lens_mask: unused by the reference forward
    const float* Wqkv  = (const float*)d_in[4];
    const float* Wproj = (const float*)d_in[5];
    const float* bproj = (const float*)d_in[6];
    float* out = (float*)d_out;
    char* ws = (char*)d_ws;

    f16* xf16  = (f16*)(ws + 0);
    f16* vT    = (f16*)(ws + 67108864);
    f16* xmean = (f16*)(ws + 134217728);
    f16* WT    = (f16*)(ws + 138412032);
    f16* WpT   = (f16*)(ws + 139984896);
    f16* qb    = (f16*)(ws + 140509184);
    f16* kb    = (f16*)(ws + 144703488);
    f16* Pm    = (f16*)(ws + 148897792);
    f16* ypre  = xf16;   // xf16 dead after V GEMM; PV writes here, PROJ reads

    prep_kernel<<<dim3(8192), dim3(256), 0, stream>>>(
        x, mask, Wqkv, Wproj, xf16, xmean, WT, WpT);
    gemm128<MODE_QK><<<dim3(8, 32), dim3(256), 0, stream>>>(
        xf16, xmean, WT, qb, kb, nullptr, nullptr);
    gemm128<MODE_V><<<dim3(4, 4, 128), dim3(256), 0, stream>>>(
        WT + 1024 * 512, nullptr, xf16, vT, nullptr, nullptr, nullptr);
    qk_softmax_kernel<<<dim3(8, 64), dim3(256), 0, stream>>>(qb, kb, Pm);
    gemm128<MODE_PV><<<dim3(8, 4, 64), dim3(256), 0, stream>>>(
        Pm, nullptr, vT, ypre, nullptr, nullptr, nullptr);
    gemm128<MODE_PROJ><<<dim3(4, 512), dim3(256), 0, stream>>>(
        ypre, nullptr, WpT, nullptr, nullptr, out, bproj);
}

// Round 3
// 421.875 us; speedup vs baseline: 1.1080x; 1.0397x over previous
//
#include <hip/hip_runtime.h>

typedef _Float16 f16;
typedef __attribute__((ext_vector_type(8))) _Float16 half8;
typedef __attribute__((ext_vector_type(2))) _Float16 half2v;
typedef __attribute__((ext_vector_type(4))) float float4v;

#define MODE_QK 0
#define MODE_V 1
#define MODE_PV 2
#define MODE_PROJ 3

// B=8 N=512 P=16 C=512 H=8 HD=64 E=1024
// ws layout (bytes):
//   0         : xf16 [B,N,P,C] f16 (67108864)   -> reused as ypre [B,N,P,C]
//   67108864  : vT   [B,H,E',N] f16 (67108864)  (E' channel order = p*64+dd)
//   134217728 : xmean[B,N,C]   f16 (4194304)
//   138412032 : WT   [1536,512]f16 (1572864)    (Wqkv transposed)
//   139984896 : WpT  [512,512] f16 (524288)
//   140509184 : q    [B,H,N,64]f16 (4194304)
//   144703488 : k    [B,H,N,64]f16 (4194304)
//   148897792 : P    [B,H,N,N] f16 (33554432)

__device__ __forceinline__ void gload16(const f16* g, f16* l) {
    __builtin_amdgcn_global_load_lds(
        (const __attribute__((address_space(1))) void*)g,
        (__attribute__((address_space(3))) void*)l, 16, 0, 0);
}

// merged: blocks [0,4096) do x prep; blocks [4096,8192) do weight transpose
__global__ __launch_bounds__(256) void prep_kernel(
    const float* __restrict__ x, const float* __restrict__ mask,
    const float* __restrict__ Wqkv, const float* __restrict__ Wproj,
    f16* __restrict__ xf, f16* __restrict__ xmean,
    f16* __restrict__ WT, f16* __restrict__ WpT)
{
    if (blockIdx.x >= 4096) {
        int idx = (blockIdx.x - 4096) * 256 + threadIdx.x;   // 1048576 total
        if (idx < 1536 * 512) {
            int d = idx >> 9, c = idx & 511;
            WT[idx] = (f16)Wqkv[c * 1536 + d];
        } else {
            int i2 = idx - 1536 * 512;
            int d = i2 >> 9, c = i2 & 511;
            WpT[i2] = (f16)Wproj[c * 512 + d];
        }
        return;
    }
    int bn = blockIdx.x;           // b*512+n
    int t = threadIdx.x;           // 256
    const float* xrow = x + (size_t)bn * 16 * 512;
    const float* mrow = mask + (size_t)bn * 16;
    float msum = 0.f;
    #pragma unroll
    for (int p = 0; p < 16; p++) msum += mrow[p];
    int c = t * 2;
    float a0 = 0.f, a1 = 0.f;
    #pragma unroll
    for (int p = 0; p < 16; p++) {
        float2 v = *(const float2*)(xrow + p * 512 + c);
        float m = mrow[p];
        a0 += m * v.x; a1 += m * v.y;
        half2v h; h[0] = (f16)v.x; h[1] = (f16)v.y;
        *(half2v*)(xf + (size_t)bn * 16 * 512 + p * 512 + c) = h;
    }
    float inv = 1.f / msum;
    half2v hm; hm[0] = (f16)(a0 * inv); hm[1] = (f16)(a1 * inv);
    *(half2v*)(xmean + (size_t)bn * 512 + c) = hm;
}

// 128x128 tile, K=512, BK=32, 256 threads = 4 waves in 2x2; each wave 64x64
// (4x4 fragments of 16x16x32). A,B staged via global_load_lds width=16 into a
// DOUBLE-BUFFERED LDS pair: per iter {barrier; issue next-tile loads; ds_read
// + MFMA current} (2-phase, T3-minimum).
// T1: bijective chunked XCD swizzle (L=(p%8)*chunk+p/8), tile decode x-fastest
//     so operand-sharing block groups co-reside on one XCD's L2.
// T2: both-sides XOR swizzle of the 16B slot within each 64B LDS row
//     (s' = s ^ ((row>>1)&3)): staging pre-swizzles the GLOBAL source offset
//     (LDS dest stays linear for global_load_lds), frag reads XOR quad.
//     Kills the 8-way quarter-wave bank conflict of the naive layout.
// MFMA A/B frag: row = lane&15, k = (lane>>4)*8 + j.
// C/D: col = lane&15, row = (lane>>4)*4 + reg.
// Epilogue: per-WAVE private LDS bounce in half-tiles (32KB total LDS ->
// 5 blocks/CU), no barriers, coalesced half8/float4 stores.
template<int MODE, int NXB, int NYB>
__global__ __launch_bounds__(256) void gemm128(
    const f16* __restrict__ pA, const f16* __restrict__ pA2,
    const f16* __restrict__ pB,
    f16* __restrict__ outa, f16* __restrict__ outb,
    float* __restrict__ outf, const float* __restrict__ bias)
{
    // 32768 B: K-loop uses all of it as 2x(As 8KB + Bs 8KB);
    // epilogue reuses [0, ...) as 4 per-wave bounce regions.
    __shared__ __align__(16) f16 sm[16384];
    const int t = threadIdx.x;
    const int lane = t & 63;
    const int w = t >> 6;
    const int wm = w & 1, wn = w >> 1;
    const int quad = lane >> 4, l15 = lane & 15;

    // T1 XCD swizzle: physical p -> XCD p%8; give each XCD a contiguous
    // chunk of logical tiles (grid sizes are all multiples of 8).
    const int chunk = (int)gridDim.x >> 3;
    const int L = ((int)blockIdx.x & 7) * chunk + ((int)blockIdx.x >> 3);
    const int xb = L & ((1 << NXB) - 1);
    const int rest = L >> NXB;
    const int yb = rest & ((1 << NYB) - 1);
    const int z = rest >> NYB;
    const int n0 = xb * 128;
    const int m0 = yb * 128;
    int vb = 0, vp = 0;

    const f16* Abase; size_t sA;
    const f16* Bbase; size_t sB;
    if constexpr (MODE == MODE_QK) {
        if (n0 < 512) { Abase = pA;  sA = 8192; }   // x p=0 slice
        else          { Abase = pA2; sA = 512;  }   // xmean
        Bbase = pB; sB = 512;                       // WT rows
    } else if constexpr (MODE == MODE_V) {
        vb = z >> 4; vp = z & 15;
        Abase = pA; sA = 512;                       // WvT rows
        Bbase = pB + ((size_t)vb * 512 * 16 + vp) * 512; sB = 8192; // x[b,:,p,:]
    } else if constexpr (MODE == MODE_PV) {
        Abase = pA + (size_t)z * 512 * 512; sA = 512;   // P rows
        Bbase = pB + (size_t)z * 1024 * 512; sB = 512;  // vT rows
    } else {
        Abase = pA; sA = 512;                       // ypre rows
        Bbase = pB; sB = 512;                       // WpT rows
    }

    // staging: A tile = 8 chunks of 16 rows (1024 B each); wave w owns
    // chunks {w, w+4}. lane covers row-in-chunk = lane>>2; 16B slot is
    // source-pre-swizzled: s_global = (lane&3) ^ ((row>>1)&3).
    const int rlo = (lane >> 2);
    const int kof = (((lane & 3) ^ ((rlo >> 1) & 3)) * 8);
    const f16* ga0 = Abase + (size_t)(m0 + w * 16 + rlo) * sA + kof;
    const f16* ga1 = Abase + (size_t)(m0 + (w + 4) * 16 + rlo) * sA + kof;
    const f16* gb0 = Bbase + (size_t)(n0 + w * 16 + rlo) * sB + kof;
    const f16* gb1 = Bbase + (size_t)(n0 + (w + 4) * 16 + rlo) * sB + kof;

    float4v acc[4][4];
    #pragma unroll
    for (int i = 0; i < 4; i++)
        #pragma unroll
        for (int j = 0; j < 4; j++)
            acc[i][j] = (float4v){0.f, 0.f, 0.f, 0.f};

    // prologue: stage K-tile 0 into buffer 0
    {
        f16* d = sm;
        gload16(ga0, d + w * 512); gload16(ga1, d + (w + 4) * 512);
        gload16(gb0, d + 4096 + w * 512); gload16(gb1, d + 4096 + (w + 4) * 512);
        ga0 += 32; ga1 += 32; gb0 += 32; gb1 += 32;
    }
    const int sws = (l15 >> 1) & 3;         // T2 read-side swizzle
    int cur = 0;
    for (int kt = 0; kt < 16; kt++) {
        __syncthreads();   // drains vmcnt: buf[cur] ready (all waves); prior
                           // reads of buf[cur^1] finished -> safe to overwrite
        if (kt < 15) {
            f16* d = sm + (cur ^ 1) * 8192;
            gload16(ga0, d + w * 512); gload16(ga1, d + (w + 4) * 512);
            gload16(gb0, d + 4096 + w * 512); gload16(gb1, d + 4096 + (w + 4) * 512);
            ga0 += 32; ga1 += 32; gb0 += 32; gb1 += 32;
        }
        const f16* Asr = sm + cur * 8192;
        const f16* Bsr = Asr + 4096;
        half8 af[4], bf[4];
        #pragma unroll
        for (int mi = 0; mi < 4; mi++)
            af[mi] = *(const half8*)&Asr[(wm * 64 + mi * 16 + l15) * 32 +
                                         ((quad ^ sws) * 8)];
        #pragma unroll
        for (int ni = 0; ni < 4; ni++)
            bf[ni] = *(const half8*)&Bsr[(wn * 64 + ni * 16 + l15) * 32 +
                                         ((quad ^ sws) * 8)];
        #pragma unroll
        for (int mi = 0; mi < 4; mi++)
            #pragma unroll
            for (int ni = 0; ni < 4; ni++)
                acc[mi][ni] = __builtin_amdgcn_mfma_f32_16x16x32_f16(
                    af[mi], bf[ni], acc[mi][ni], 0, 0, 0);
        cur ^= 1;
    }

    __syncthreads();   // all waves done reading LDS; reuse as per-wave bounce

    if constexpr (MODE == MODE_PROJ) {
        // per-wave region: 16 rows x 68 f32 (4352 B), four 16-row passes
        float* pwf = (float*)sm + w * 1088;
        const int rr4 = lane >> 4, c4c = (lane & 15) * 4;
        float4v bb = *(const float4v*)&bias[n0 + wn * 64 + c4c];
        #pragma unroll
        for (int mi = 0; mi < 4; mi++) {
            #pragma unroll
            for (int ni = 0; ni < 4; ni++)
                #pragma unroll
                for (int i = 0; i < 4; i++)
                    pwf[(quad * 4 + i) * 68 + ni * 16 + l15] = acc[mi][ni][i];
            // wave-local write->read; compiler inserts lgkm waits
            #pragma unroll
            for (int s = 0; s < 4; s++) {
                int r = s * 4 + rr4;
                float4v v = *(const float4v*)&pwf[r * 68 + c4c];
                *(float4v*)&outf[(size_t)(m0 + wm * 64 + mi * 16 + r) * 512 +
                                 n0 + wn * 64 + c4c] = v + bb;
            }
        }
    } else {
        // per-wave region: 32 rows x 72 f16 (4608 B), two 32-row passes
        f16* pw = sm + w * 2304;
        const int rr8 = lane >> 3, c8 = (lane & 7) * 8;
        #pragma unroll
        for (int hf = 0; hf < 2; hf++) {
            #pragma unroll
            for (int mh = 0; mh < 2; mh++) {
                int mi = hf * 2 + mh;
                #pragma unroll
                for (int ni = 0; ni < 4; ni++)
                    #pragma unroll
                    for (int i = 0; i < 4; i++)
                        pw[(mh * 16 + quad * 4 + i) * 72 + ni * 16 + l15] =
                            (f16)acc[mi][ni][i];
            }
            #pragma unroll
            for (int s = 0; s < 4; s++) {
                int r = s * 8 + rr8;
                half8 v = *(const half8*)&pw[r * 72 + c8];
                int gr = m0 + wm * 64 + hf * 32 + r;
                int gc = n0 + wn * 64 + c8;
                if constexpr (MODE == MODE_QK) {
                    int b = gr >> 9, n = gr & 511;
                    if (gc < 512)
                        *(half8*)&outa[(((size_t)(b * 8 + (gc >> 6))) * 512 + n) * 64 + (gc & 63)] = v;
                    else {
                        int jj = gc - 512;
                        *(half8*)&outb[(((size_t)(b * 8 + (jj >> 6))) * 512 + n) * 64 + (jj & 63)] = v;
                    }
                } else if constexpr (MODE == MODE_V) {
                    int h = gr >> 6, dd = gr & 63;   // e' order: p*64+dd
                    *(half8*)&outa[(((size_t)(vb * 8 + h)) * 1024 + vp * 64 + dd) * 512 + gc] = v;
                } else { // MODE_PV: direct ypre store, e' = p*64+dd
                    int p = gc >> 6, dd = gc & 63;
                    int b = z >> 3, h = z & 7;
                    *(half8*)&outa[((size_t)(b * 512 + gr) * 16 + p) * 512 + h * 64 + dd] = v;
                }
            }
        }
    }
}

// Fused S = q k^T * 0.125 and row softmax, writes P (f16, normalized).
// 1-D grid 512 with T1 XCD swizzle: the 8 n-tile blocks of one bh are
// consecutive logical -> same XCD -> k panel (64KB) L2-shared.
// k staged in 4 chunks of [128][64] f16 (16 KB) via global_load_lds with
// both-sides XOR swizzle (col16 ^= row&7) so ds_read_b128 is ~2-way.
// q fragments loaded directly from global (L2-hot, 2 loads).
// P written via per-wave LDS bounce ([16][264] f16) as half8 stores.
__global__ __launch_bounds__(256) void qk_softmax_kernel(
    const f16* __restrict__ q, const f16* __restrict__ k, f16* __restrict__ Pout)
{
    __shared__ __align__(16) f16 sm[16896];   // 33 KB: k-chunk 8192 f16 + bounce 4*4224
    const int t = threadIdx.x;
    const int lane = t & 63, w = t >> 6;
    const int quad = lane >> 4, l15 = lane & 15;
    const int L = ((int)blockIdx.x & 7) * 64 + ((int)blockIdx.x >> 3);
    const int bh = L >> 3;
    const int n0 = (L & 7) * 64;

    const f16* kbase = k + (size_t)bh * 512 * 64;
    const f16* qp = q + ((size_t)bh * 512 + n0 + w * 16 + l15) * 64 + quad * 8;
    half8 a0 = *(const half8*)qp;
    half8 a1 = *(const half8*)(qp + 32);

    float4v acc[32];
    #pragma unroll
    for (int f = 0; f < 32; f++) acc[f] = (float4v){0.f, 0.f, 0.f, 0.f};

    const int srow = lane >> 3, scol = lane & 7;
    #pragma unroll
    for (int c = 0; c < 4; c++) {
        __syncthreads();           // prior chunk reads done
        #pragma unroll
        for (int i = 0; i < 4; i++) {
            int ci2 = w * 4 + i;
            int row = ci2 * 8 + srow;
            // linear LDS dest; source pre-swizzled (rule: both-sides-or-neither)
            gload16(kbase + c * 8192 + row * 64 + ((scol ^ (row & 7)) << 3),
                    sm + ci2 * 512 + lane * 8);
        }
        __syncthreads();
        #pragma unroll
        for (int fl = 0; fl < 8; fl++) {
            int row16 = fl * 16 + l15;
            int sw = row16 & 7;
            half8 b0 = *(const half8*)&sm[row16 * 64 + ((quad ^ sw) << 3)];
            half8 b1 = *(const half8*)&sm[row16 * 64 + (((quad + 4) ^ sw) << 3)];
            acc[c * 8 + fl] = __builtin_amdgcn_mfma_f32_16x16x32_f16(
                a0, b0, acc[c * 8 + fl], 0, 0, 0);
            acc[c * 8 + fl] = __builtin_amdgcn_mfma_f32_16x16x32_f16(
                a1, b1, acc[c * 8 + fl], 0, 0, 0);
        }
    }

    float mx0 = -3e38f, mx1 = -3e38f, mx2 = -3e38f, mx3 = -3e38f;
    #pragma unroll
    for (int f = 0; f < 32; f++) {
        mx0 = fmaxf(mx0, acc[f][0]); mx1 = fmaxf(mx1, acc[f][1]);
        mx2 = fmaxf(mx2, acc[f][2]); mx3 = fmaxf(mx3, acc[f][3]);
    }
    #pragma unroll
    for (int off = 1; off < 16; off <<= 1) {
        mx0 = fmaxf(mx0, __shfl_xor(mx0, off));
        mx1 = fmaxf(mx1, __shfl_xor(mx1, off));
        mx2 = fmaxf(mx2, __shfl_xor(mx2, off));
        mx3 = fmaxf(mx3, __shfl_xor(mx3, off));
    }
    float s0 = 0.f, s1 = 0.f, s2 = 0.f, s3 = 0.f;
    #pragma unroll
    for (int f = 0; f < 32; f++) {
        float e0 = __expf(0.125f * (acc[f][0] - mx0));
        float e1 = __expf(0.125f * (acc[f][1] - mx1));
        float e2 = __expf(0.125f * (acc[f][2] - mx2));
        float e3 = __expf(0.125f * (acc[f][3] - mx3));
        acc[f][0] = e0; acc[f][1] = e1; acc[f][2] = e2; acc[f][3] = e3;
        s0 += e0; s1 += e1; s2 += e2; s3 += e3;
    }
    #pragma unroll
    for (int off = 1; off < 16; off <<= 1) {
        s0 += __shfl_xor(s0, off);
        s1 += __shfl_xor(s1, off);
        s2 += __shfl_xor(s2, off);
        s3 += __shfl_xor(s3, off);
    }
    float r0 = 1.f / s0, r1 = 1.f / s1, r2 = 1.f / s2, r3 = 1.f / s3;

    __syncthreads();               // all waves done with k chunks; reuse sm
    f16* pb = sm + w * 4224;       // per-wave [16][264] f16 bounce
    const int rr = lane >> 2, cb = (lane & 3) * 64;
    #pragma unroll
    for (int cc = 0; cc < 2; cc++) {
        #pragma unroll
        for (int ff = 0; ff < 16; ff++) {
            int f = cc * 16 + ff;
            pb[(quad * 4 + 0) * 264 + ff * 16 + l15] = (f16)(acc[f][0] * r0);
            pb[(quad * 4 + 1) * 264 + ff * 16 + l15] = (f16)(acc[f][1] * r1);
            pb[(quad * 4 + 2) * 264 + ff * 16 + l15] = (f16)(acc[f][2] * r2);
            pb[(quad * 4 + 3) * 264 + ff * 16 + l15] = (f16)(acc[f][3] * r3);
        }
        size_t gb = ((size_t)bh * 512 + n0 + w * 16 + rr) * 512 + cc * 256 + cb;
        #pragma unroll
        for (int s = 0; s < 8; s++) {
            half8 v = *(const half8*)&pb[rr * 264 + cb + s * 8];
            *(half8*)&Pout[gb + s * 8] = v;
        }
    }
}

extern "C" void kernel_launch(void* const* d_in, const int* in_sizes, int n_in,
                              void* d_out, int out_size, void* d_ws, size_t ws_size,
                              hipStream_t stream)
{
    (void)in_sizes; (void)n_in; (void)out_size; (void)ws_size;
    const float* x     = (const float*)d_in[0];
    const float* mask  = (const float*)d_in[1];
    // d_in[2] lens, d_in[3] lens_mask: unused by the reference forward
    const float* Wqkv  = (const float*)d_in[4];
    const float* Wproj = (const float*)d_in[5];
    const float* bproj = (const float*)d_in[6];
    float* out = (float*)d_out;
    char* ws = (char*)d_ws;

    f16* xf16  = (f16*)(ws + 0);
    f16* vT    = (f16*)(ws + 67108864);
    f16* xmean = (f16*)(ws + 134217728);
    f16* WT    = (f16*)(ws + 138412032);
    f16* WpT   = (f16*)(ws + 139984896);
    f16* qb    = (f16*)(ws + 140509184);
    f16* kb    = (f16*)(ws + 144703488);
    f16* Pm    = (f16*)(ws + 148897792);
    f16* ypre  = xf16;   // xf16 dead after V GEMM; PV writes here, PROJ reads

    prep_kernel<<<dim3(8192), dim3(256), 0, stream>>>(
        x, mask, Wqkv, Wproj, xf16, xmean, WT, WpT);
    // 1-D grids; logical tiles decoded x-fastest after XCD chunk swizzle.
    gemm128<MODE_QK, 3, 5><<<dim3(256), dim3(256), 0, stream>>>(
        xf16, xmean, WT, qb, kb, nullptr, nullptr);
    gemm128<MODE_V, 2, 2><<<dim3(2048), dim3(256), 0, stream>>>(
        WT + 1024 * 512, nullptr, xf16, vT, nullptr, nullptr, nullptr);
    qk_softmax_kernel<<<dim3(512), dim3(256), 0, stream>>>(qb, kb, Pm);
    gemm128<MODE_PV, 3, 2><<<dim3(2048), dim3(256), 0, stream>>>(
        Pm, nullptr, vT, ypre, nullptr, nullptr, nullptr);
    gemm128<MODE_PROJ, 2, 9><<<dim3(2048), dim3(256), 0, stream>>>(
        ypre, nullptr, WpT, nullptr, nullptr, out, bproj);
}

// Round 4
// 405.325 us; speedup vs baseline: 1.1532x; 1.0408x over previous
//
#include <hip/hip_runtime.h>

typedef _Float16 f16;
typedef __attribute__((ext_vector_type(8))) _Float16 half8;
typedef __attribute__((ext_vector_type(2))) _Float16 half2v;
typedef __attribute__((ext_vector_type(4))) float float4v;

#define MODE_QK 0
#define MODE_V 1
#define MODE_PV 2
#define MODE_PROJ 3

// B=8 N=512 P=16 C=512 H=8 HD=64 E=1024
// ws layout (bytes):
//   0         : xf16 [B,N,P,C] f16 (67108864)   -> reused as ypre [B,N,P,C]
//   67108864  : vT   [B,H,E',N] f16 (67108864)  (E' channel order = p*64+dd)
//   134217728 : xmean[B,N,C]   f16 (4194304)
//   138412032 : WT   [1536,512]f16 (1572864)    (Wqkv transposed)
//   139984896 : WpT  [512,512] f16 (524288)
//   140509184 : q    [B,H,N,64]f16 (4194304)
//   144703488 : k    [B,H,N,64]f16 (4194304)
//   148897792 : P    [B,H,N,N] f16 (33554432)

__device__ __forceinline__ void gload16(const f16* g, f16* l) {
    __builtin_amdgcn_global_load_lds(
        (const __attribute__((address_space(1))) void*)g,
        (__attribute__((address_space(3))) void*)l, 16, 0, 0);
}

// merged: blocks [0,4096) do x prep; blocks [4096,8192) do weight transpose
__global__ __launch_bounds__(256) void prep_kernel(
    const float* __restrict__ x, const float* __restrict__ mask,
    const float* __restrict__ Wqkv, const float* __restrict__ Wproj,
    f16* __restrict__ xf, f16* __restrict__ xmean,
    f16* __restrict__ WT, f16* __restrict__ WpT)
{
    if (blockIdx.x >= 4096) {
        int idx = (blockIdx.x - 4096) * 256 + threadIdx.x;   // 1048576 total
        if (idx < 1536 * 512) {
            int d = idx >> 9, c = idx & 511;
            WT[idx] = (f16)Wqkv[c * 1536 + d];
        } else {
            int i2 = idx - 1536 * 512;
            int d = i2 >> 9, c = i2 & 511;
            WpT[i2] = (f16)Wproj[c * 512 + d];
        }
        return;
    }
    int bn = blockIdx.x;           // b*512+n
    int t = threadIdx.x;           // 256
    const float* xrow = x + (size_t)bn * 16 * 512;
    const float* mrow = mask + (size_t)bn * 16;
    float msum = 0.f;
    #pragma unroll
    for (int p = 0; p < 16; p++) msum += mrow[p];
    int c = t * 2;
    float a0 = 0.f, a1 = 0.f;
    #pragma unroll
    for (int p = 0; p < 16; p++) {
        float2 v = *(const float2*)(xrow + p * 512 + c);
        float m = mrow[p];
        a0 += m * v.x; a1 += m * v.y;
        half2v h; h[0] = (f16)v.x; h[1] = (f16)v.y;
        *(half2v*)(xf + (size_t)bn * 16 * 512 + p * 512 + c) = h;
    }
    float inv = 1.f / msum;
    half2v hm; hm[0] = (f16)(a0 * inv); hm[1] = (f16)(a1 * inv);
    *(half2v*)(xmean + (size_t)bn * 512 + c) = hm;
}

// 128x128 tile, K=512, BK=32, 256 threads = 4 waves in 2x2; each wave 64x64
// (4x4 fragments of 16x16x32).
// T4 counted-vmcnt 3-deep ring: prologue stages S0,S1; each iter
// {s_waitcnt vmcnt(4); s_barrier; stage S(t+2); ds_read+MFMA buf(t)} so every
// staging set gets ~2 compute phases of latency cover; vmcnt never drains to 0
// in the main loop (the m97-structure stall was the per-iter vmcnt(0) drain).
// T1: bijective chunked XCD swizzle (L=(p%8)*chunk+p/8), tile decode x-fastest.
// T2: both-sides XOR swizzle of the 16B slot within each 64B LDS row
//     (source-pre-swizzled global offset, linear LDS dest, read XORs quad).
// MFMA A/B frag: row = lane&15, k = (lane>>4)*8 + j.
// C/D: col = lane&15, row = (lane>>4)*4 + reg.
// Epilogue: per-WAVE private LDS bounce (no barriers), coalesced stores.
template<int MODE, int NXB, int NYB>
__global__ __launch_bounds__(256) void gemm128(
    const f16* __restrict__ pA, const f16* __restrict__ pA2,
    const f16* __restrict__ pB,
    f16* __restrict__ outa, f16* __restrict__ outb,
    float* __restrict__ outf, const float* __restrict__ bias)
{
    // 49152 B: ring of 3 x (As 8KB + Bs 8KB); epilogue reuses as bounce.
    __shared__ __align__(16) f16 sm[24576];
    const int t = threadIdx.x;
    const int lane = t & 63;
    const int w = t >> 6;
    const int wm = w & 1, wn = w >> 1;
    const int quad = lane >> 4, l15 = lane & 15;

    // T1 XCD swizzle: physical p -> XCD p%8; each XCD gets a contiguous
    // chunk of logical tiles (grid sizes are all multiples of 8).
    const int chunk = (int)gridDim.x >> 3;
    const int L = ((int)blockIdx.x & 7) * chunk + ((int)blockIdx.x >> 3);
    const int xb = L & ((1 << NXB) - 1);
    const int rest = L >> NXB;
    const int yb = rest & ((1 << NYB) - 1);
    const int z = rest >> NYB;
    const int n0 = xb * 128;
    const int m0 = yb * 128;
    int vb = 0, vp = 0;

    const f16* Abase; size_t sA;
    const f16* Bbase; size_t sB;
    if constexpr (MODE == MODE_QK) {
        if (n0 < 512) { Abase = pA;  sA = 8192; }   // x p=0 slice
        else          { Abase = pA2; sA = 512;  }   // xmean
        Bbase = pB; sB = 512;                       // WT rows
    } else if constexpr (MODE == MODE_V) {
        vb = z >> 4; vp = z & 15;
        Abase = pA; sA = 512;                       // WvT rows
        Bbase = pB + ((size_t)vb * 512 * 16 + vp) * 512; sB = 8192; // x[b,:,p,:]
    } else if constexpr (MODE == MODE_PV) {
        Abase = pA + (size_t)z * 512 * 512; sA = 512;   // P rows
        Bbase = pB + (size_t)z * 1024 * 512; sB = 512;  // vT rows
    } else {
        Abase = pA; sA = 512;                       // ypre rows
        Bbase = pB; sB = 512;                       // WpT rows
    }

    // staging: A tile = 8 chunks of 16 rows (1024 B each); wave w owns
    // chunks {w, w+4}. lane covers row-in-chunk = lane>>2; 16B slot is
    // source-pre-swizzled: s_global = (lane&3) ^ ((row>>1)&3).
    const int rlo = (lane >> 2);
    const int kof = (((lane & 3) ^ ((rlo >> 1) & 3)) * 8);
    const f16* ga0 = Abase + (size_t)(m0 + w * 16 + rlo) * sA + kof;
    const f16* ga1 = Abase + (size_t)(m0 + (w + 4) * 16 + rlo) * sA + kof;
    const f16* gb0 = Bbase + (size_t)(n0 + w * 16 + rlo) * sB + kof;
    const f16* gb1 = Bbase + (size_t)(n0 + (w + 4) * 16 + rlo) * sB + kof;

    float4v acc[4][4];
    #pragma unroll
    for (int i = 0; i < 4; i++)
        #pragma unroll
        for (int j = 0; j < 4; j++)
            acc[i][j] = (float4v){0.f, 0.f, 0.f, 0.f};

    const int sws = (l15 >> 1) & 3;         // T2 read-side swizzle

#define STAGE(dst)                                                     \
    do {                                                               \
        f16* d_ = (dst);                                               \
        gload16(ga0, d_ + w * 512); gload16(ga1, d_ + (w + 4) * 512);  \
        gload16(gb0, d_ + 4096 + w * 512);                             \
        gload16(gb1, d_ + 4096 + (w + 4) * 512);                       \
        ga0 += 32; ga1 += 32; gb0 += 32; gb1 += 32;                    \
    } while (0)

#define COMPUTE(buf)                                                         \
    do {                                                                     \
        const f16* Asr_ = (buf);                                             \
        const f16* Bsr_ = Asr_ + 4096;                                       \
        half8 af[4], bf[4];                                                  \
        _Pragma("unroll")                                                    \
        for (int mi = 0; mi < 4; mi++)                                       \
            af[mi] = *(const half8*)&Asr_[(wm * 64 + mi * 16 + l15) * 32 +   \
                                          ((quad ^ sws) * 8)];               \
        _Pragma("unroll")                                                    \
        for (int ni = 0; ni < 4; ni++)                                       \
            bf[ni] = *(const half8*)&Bsr_[(wn * 64 + ni * 16 + l15) * 32 +   \
                                          ((quad ^ sws) * 8)];               \
        _Pragma("unroll")                                                    \
        for (int mi = 0; mi < 4; mi++)                                       \
            _Pragma("unroll")                                                \
            for (int ni = 0; ni < 4; ni++)                                   \
                acc[mi][ni] = __builtin_amdgcn_mfma_f32_16x16x32_f16(        \
                    af[mi], bf[ni], acc[mi][ni], 0, 0, 0);                   \
    } while (0)

    f16* pc = sm;            // compute buffer (t)
    f16* pn = sm + 8192;     // next (t+1)
    f16* pf = sm + 16384;    // staging target (t+2)
    // prologue: stage S0 -> pc, S1 -> pn (8 loads outstanding per wave)
    STAGE(pc);
    STAGE(pn);
    for (int kt = 0; kt < 14; kt++) {
        // oldest 4 loads (set kt) done; newest 4 (set kt+1) stay in flight
        asm volatile("s_waitcnt vmcnt(4)" ::: "memory");
        __builtin_amdgcn_s_barrier();
        __builtin_amdgcn_sched_barrier(0);
        STAGE(pf);           // set kt+2 -> buffer read at kt-1 (reads done)
        COMPUTE(pc);
        f16* tmp = pc; pc = pn; pn = pf; pf = tmp;
    }
    asm volatile("s_waitcnt vmcnt(4)" ::: "memory");   // S14 done
    __builtin_amdgcn_s_barrier();
    __builtin_amdgcn_sched_barrier(0);
    COMPUTE(pc);             // kt = 14
    { f16* tmp = pc; pc = pn; pn = pf; pf = tmp; }
    asm volatile("s_waitcnt vmcnt(0)" ::: "memory");   // S15 done
    __builtin_amdgcn_s_barrier();
    __builtin_amdgcn_sched_barrier(0);
    COMPUTE(pc);             // kt = 15
#undef STAGE
#undef COMPUTE

    __syncthreads();   // all waves done reading LDS; reuse as per-wave bounce

    if constexpr (MODE == MODE_PROJ) {
        // per-wave region: 16 rows x 68 f32 (4352 B), four 16-row passes
        float* pwf = (float*)sm + w * 1088;
        const int rr4 = lane >> 4, c4c = (lane & 15) * 4;
        float4v bb = *(const float4v*)&bias[n0 + wn * 64 + c4c];
        #pragma unroll
        for (int mi = 0; mi < 4; mi++) {
            #pragma unroll
            for (int ni = 0; ni < 4; ni++)
                #pragma unroll
                for (int i = 0; i < 4; i++)
                    pwf[(quad * 4 + i) * 68 + ni * 16 + l15] = acc[mi][ni][i];
            // wave-local write->read; compiler inserts lgkm waits
            #pragma unroll
            for (int s = 0; s < 4; s++) {
                int r = s * 4 + rr4;
                float4v v = *(const float4v*)&pwf[r * 68 + c4c];
                *(float4v*)&outf[(size_t)(m0 + wm * 64 + mi * 16 + r) * 512 +
                                 n0 + wn * 64 + c4c] = v + bb;
            }
        }
    } else {
        // per-wave region: 32 rows x 72 f16 (4608 B), two 32-row passes
        f16* pw = sm + w * 2304;
        const int rr8 = lane >> 3, c8 = (lane & 7) * 8;
        #pragma unroll
        for (int hf = 0; hf < 2; hf++) {
            #pragma unroll
            for (int mh = 0; mh < 2; mh++) {
                int mi = hf * 2 + mh;
                #pragma unroll
                for (int ni = 0; ni < 4; ni++)
                    #pragma unroll
                    for (int i = 0; i < 4; i++)
                        pw[(mh * 16 + quad * 4 + i) * 72 + ni * 16 + l15] =
                            (f16)acc[mi][ni][i];
            }
            #pragma unroll
            for (int s = 0; s < 4; s++) {
                int r = s * 8 + rr8;
                half8 v = *(const half8*)&pw[r * 72 + c8];
                int gr = m0 + wm * 64 + hf * 32 + r;
                int gc = n0 + wn * 64 + c8;
                if constexpr (MODE == MODE_QK) {
                    int b = gr >> 9, n = gr & 511;
                    if (gc < 512)
                        *(half8*)&outa[(((size_t)(b * 8 + (gc >> 6))) * 512 + n) * 64 + (gc & 63)] = v;
                    else {
                        int jj = gc - 512;
                        *(half8*)&outb[(((size_t)(b * 8 + (jj >> 6))) * 512 + n) * 64 + (jj & 63)] = v;
                    }
                } else if constexpr (MODE == MODE_V) {
                    int h = gr >> 6, dd = gr & 63;   // e' order: p*64+dd
                    *(half8*)&outa[(((size_t)(vb * 8 + h)) * 1024 + vp * 64 + dd) * 512 + gc] = v;
                } else { // MODE_PV: direct ypre store, e' = p*64+dd
                    int p = gc >> 6, dd = gc & 63;
                    int b = z >> 3, h = z & 7;
                    *(half8*)&outa[((size_t)(b * 512 + gr) * 16 + p) * 512 + h * 64 + dd] = v;
                }
            }
        }
    }
}

// Fused S = q k^T * 0.125 and row softmax, writes P (f16, normalized).
// 1-D grid 512 with T1 XCD swizzle (8 n-tile blocks of one bh on one XCD).
// Whole k panel [512][64] f16 (64 KB) staged up front via global_load_lds
// (grid = exactly 2 blocks/CU, so 64 KB LDS costs no occupancy) with
// both-sides XOR swizzle; ONE vmcnt(0)+barrier instead of 8 barriers.
// q fragments loaded directly from global, overlapped with staging.
// P written via per-wave LDS bounce ([16][264] f16) as half8 stores.
__global__ __launch_bounds__(256) void qk_softmax_kernel(
    const f16* __restrict__ q, const f16* __restrict__ k, f16* __restrict__ Pout)
{
    __shared__ __align__(16) f16 sm[32768];   // 64 KB k panel; reused as bounce
    const int t = threadIdx.x;
    const int lane = t & 63, w = t >> 6;
    const int quad = lane >> 4, l15 = lane & 15;
    const int L = ((int)blockIdx.x & 7) * 64 + ((int)blockIdx.x >> 3);
    const int bh = L >> 3;
    const int n0 = (L & 7) * 64;

    const f16* kbase = k + (size_t)bh * 512 * 64;

    // stage all 512 rows x 64 f16: 16 gload16 per thread; linear LDS dest,
    // source pre-swizzled (slot ^= row&7)
    #pragma unroll
    for (int i = 0; i < 16; i++) {
        int cid = i * 256 + t;
        int row = cid >> 3, off = cid & 7;
        gload16(kbase + row * 64 + ((off ^ (row & 7)) << 3),
                sm + i * 2048 + w * 512 + (lane & 63) * 8);
    }
    // q loads overlap the staging
    const f16* qp = q + ((size_t)bh * 512 + n0 + w * 16 + l15) * 64 + quad * 8;
    half8 a0 = *(const half8*)qp;
    half8 a1 = *(const half8*)(qp + 32);

    asm volatile("s_waitcnt vmcnt(0)" ::: "memory");
    __builtin_amdgcn_s_barrier();
    __builtin_amdgcn_sched_barrier(0);

    float4v acc[32];
    #pragma unroll
    for (int f = 0; f < 32; f++) acc[f] = (float4v){0.f, 0.f, 0.f, 0.f};
    #pragma unroll
    for (int fl = 0; fl < 32; fl++) {
        int row16 = fl * 16 + l15;
        int sw = row16 & 7;
        half8 b0 = *(const half8*)&sm[row16 * 64 + ((quad ^ sw) << 3)];
        half8 b1 = *(const half8*)&sm[row16 * 64 + (((quad + 4) ^ sw) << 3)];
        acc[fl] = __builtin_amdgcn_mfma_f32_16x16x32_f16(a0, b0, acc[fl], 0, 0, 0);
        acc[fl] = __builtin_amdgcn_mfma_f32_16x16x32_f16(a1, b1, acc[fl], 0, 0, 0);
    }

    float mx0 = -3e38f, mx1 = -3e38f, mx2 = -3e38f, mx3 = -3e38f;
    #pragma unroll
    for (int f = 0; f < 32; f++) {
        mx0 = fmaxf(mx0, acc[f][0]); mx1 = fmaxf(mx1, acc[f][1]);
        mx2 = fmaxf(mx2, acc[f][2]); mx3 = fmaxf(mx3, acc[f][3]);
    }
    #pragma unroll
    for (int off = 1; off < 16; off <<= 1) {
        mx0 = fmaxf(mx0, __shfl_xor(mx0, off));
        mx1 = fmaxf(mx1, __shfl_xor(mx1, off));
        mx2 = fmaxf(mx2, __shfl_xor(mx2, off));
        mx3 = fmaxf(mx3, __shfl_xor(mx3, off));
    }
    float s0 = 0.f, s1 = 0.f, s2 = 0.f, s3 = 0.f;
    #pragma unroll
    for (int f = 0; f < 32; f++) {
        float e0 = __expf(0.125f * (acc[f][0] - mx0));
        float e1 = __expf(0.125f * (acc[f][1] - mx1));
        float e2 = __expf(0.125f * (acc[f][2] - mx2));
        float e3 = __expf(0.125f * (acc[f][3] - mx3));
        acc[f][0] = e0; acc[f][1] = e1; acc[f][2] = e2; acc[f][3] = e3;
        s0 += e0; s1 += e1; s2 += e2; s3 += e3;
    }
    #pragma unroll
    for (int off = 1; off < 16; off <<= 1) {
        s0 += __shfl_xor(s0, off);
        s1 += __shfl_xor(s1, off);
        s2 += __shfl_xor(s2, off);
        s3 += __shfl_xor(s3, off);
    }
    float r0 = 1.f / s0, r1 = 1.f / s1, r2 = 1.f / s2, r3 = 1.f / s3;

    __syncthreads();               // all waves done with k panel; reuse sm
    f16* pb = sm + w * 4224;       // per-wave [16][264] f16 bounce
    const int rr = lane >> 2, cb = (lane & 3) * 64;
    #pragma unroll
    for (int cc = 0; cc < 2; cc++) {
        #pragma unroll
        for (int ff = 0; ff < 16; ff++) {
            int f = cc * 16 + ff;
            pb[(quad * 4 + 0) * 264 + ff * 16 + l15] = (f16)(acc[f][0] * r0);
            pb[(quad * 4 + 1) * 264 + ff * 16 + l15] = (f16)(acc[f][1] * r1);
            pb[(quad * 4 + 2) * 264 + ff * 16 + l15] = (f16)(acc[f][2] * r2);
            pb[(quad * 4 + 3) * 264 + ff * 16 + l15] = (f16)(acc[f][3] * r3);
        }
        size_t gb = ((size_t)bh * 512 + n0 + w * 16 + rr) * 512 + cc * 256 + cb;
        #pragma unroll
        for (int s = 0; s < 8; s++) {
            half8 v = *(const half8*)&pb[rr * 264 + cb + s * 8];
            *(half8*)&Pout[gb + s * 8] = v;
        }
    }
}

extern "C" void kernel_launch(void* const* d_in, const int* in_sizes, int n_in,
                              void* d_out, int out_size, void* d_ws, size_t ws_size,
                              hipStream_t stream)
{
    (void)in_sizes; (void)n_in; (void)out_size; (void)ws_size;
    const float* x     = (const float*)d_in[0];
    const float* mask  = (const float*)d_in[1];
    // d_in[2] lens, d_in[3] lens_mask: unused by the reference forward
    const float* Wqkv  = (const float*)d_in[4];
    const float* Wproj = (const float*)d_in[5];
    const float* bproj = (const float*)d_in[6];
    float* out = (float*)d_out;
    char* ws = (char*)d_ws;

    f16* xf16  = (f16*)(ws + 0);
    f16* vT    = (f16*)(ws + 67108864);
    f16* xmean = (f16*)(ws + 134217728);
    f16* WT    = (f16*)(ws + 138412032);
    f16* WpT   = (f16*)(ws + 139984896);
    f16* qb    = (f16*)(ws + 140509184);
    f16* kb    = (f16*)(ws + 144703488);
    f16* Pm    = (f16*)(ws + 148897792);
    f16* ypre  = xf16;   // xf16 dead after V GEMM; PV writes here, PROJ reads

    prep_kernel<<<dim3(8192), dim3(256), 0, stream>>>(
        x, mask, Wqkv, Wproj, xf16, xmean, WT, WpT);
    // 1-D grids; logical tiles decoded x-fastest after XCD chunk swizzle.
    gemm128<MODE_QK, 3, 5><<<dim3(256), dim3(256), 0, stream>>>(
        xf16, xmean, WT, qb, kb, nullptr, nullptr);
    gemm128<MODE_V, 2, 2><<<dim3(2048), dim3(256), 0, stream>>>(
        WT + 1024 * 512, nullptr, xf16, vT, nullptr, nullptr, nullptr);
    qk_softmax_kernel<<<dim3(512), dim3(256), 0, stream>>>(qb, kb, Pm);
    gemm128<MODE_PV, 3, 2><<<dim3(2048), dim3(256), 0, stream>>>(
        Pm, nullptr, vT, ypre, nullptr, nullptr, nullptr);
    gemm128<MODE_PROJ, 2, 9><<<dim3(2048), dim3(256), 0, stream>>>(
        ypre, nullptr, WpT, nullptr, nullptr, out, bproj);
}